// Round 14
// baseline (122.633 us; speedup 1.0000x reference)
//
#include <hip/hip_runtime.h>
#include <hip/hip_bf16.h>

// Problem constants
#define B 64
#define D 25000
#define K 16
#define H 128
#define E 256
#define Z 32
#define DTILE 10
#define NBLK (D / DTILE)      // 2500 blocks
#define NREP 8                // one replica per XCD (blockIdx&7 == XCD round-robin)
#define NTILE ((D + 63) / 64) // 391 transpose tiles

// ws layout: rep f32[NREP*B*K] | hiW2 f16[H*K] | w1f f16[8*64*8] | mTh f16[D*B]
#define REP_BYTES (NREP * B * K * 4)
#define HI_OFF    REP_BYTES
#define W1F_OFF   (HI_OFF + H * K * 2)
#define MT_OFF    (W1F_OFF + 8 * 64 * 8 * 2)

typedef __attribute__((ext_vector_type(8))) _Float16 half8;
typedef __attribute__((ext_vector_type(4))) _Float16 hv4;
typedef __attribute__((ext_vector_type(2))) _Float16 hv2;
typedef __attribute__((ext_vector_type(4))) float f32x4;

// prep: bid<8 zero replicas; bid==8 fp16 W2 frag table; bid==9 extended-W1 frag table;
// bid>=10: mask transpose tile -> mTh[d][b] fp16 (coalesced both sides).
__global__ __launch_bounds__(256) void prep_kernel(
    const int* __restrict__ mask, const float* __restrict__ W1,
    const float* __restrict__ b1, const float* __restrict__ W2,
    float* __restrict__ rep, _Float16* __restrict__ hiW2,
    _Float16* __restrict__ w1f, _Float16* __restrict__ mTh)
{
    const int t = threadIdx.x;
    const int bid = blockIdx.x;
    if (bid < NREP) {
        for (int i = t; i < B * K; i += 256) rep[bid * B * K + i] = 0.f;
    } else if (bid == NREP) {
        for (int i = t; i < H * K; i += 256) {
            int j = i & 7, n = (i >> 3) & 15, g = (i >> 7) & 3, s = i >> 9;
            int k = s * 32 + g * 8 + j;
            hiW2[i] = (_Float16)W2[k * K + n];
        }
    } else if (bid == NREP + 1) {
        // w1f[c][lane][j]: B[k][h=c*16+n], k=(lane>>4)*8+j; k<16->W1[1+k], 16->W1[17], 17->b1, else 0
        for (int i = t; i < 8 * 64 * 8; i += 256) {
            int j = i & 7, lane = (i >> 3) & 63, c = i >> 9;
            int g = lane >> 4, n = lane & 15;
            int k = g * 8 + j, h = c * 16 + n;
            float v;
            if (k < 16)       v = W1[(1 + k) * H + h];
            else if (k == 16) v = W1[17 * H + h];
            else if (k == 17) v = b1[h];
            else              v = 0.f;
            w1f[i] = (_Float16)v;
        }
    } else {
        __shared__ float tm[64 * 65];
        const int dt0 = (bid - NREP - 2) * 64;
        const int dn  = min(64, D - dt0);
        for (int i = t; i < 64 * 64; i += 256) {
            int bb = i >> 6, dd = i & 63;           // dd fast -> coalesced global read
            if (dd < dn) tm[dd * 65 + bb] = (float)mask[(size_t)bb * D + dt0 + dd];
        }
        __syncthreads();
        for (int i = t; i < dn * 64; i += 256) {
            int dd = i >> 6, bb = i & 63;           // bb fast -> coalesced fp16 write
            mTh[(size_t)(dt0 + dd) * 64 + bb] = (_Float16)tm[dd * 65 + bb];
        }
    }
}

// main: ZERO __syncthreads. Each wave builds a PRIVATE fp16 G copy via 8 MFMAs
// (intra-wave ds ordering = lgkmcnt only), then runs the hot loop on its own slice.
// h1 = relu(x*w0 + G) packed fp16; h2 = relu(h1@W2+b2) fp16 MFMA (b2 in C-init);
// c += mask*h2 fp32 -> XCD-local replica atomics.
__global__ __launch_bounds__(256) void partial_main_kernel(
    const float* __restrict__ x, const float* __restrict__ feat_emb,
    const float* __restrict__ feat_bias, const float* __restrict__ W1,
    const float* __restrict__ b2, const _Float16* __restrict__ hiW2,
    const _Float16* __restrict__ w1f, const _Float16* __restrict__ mTh,
    float* __restrict__ rep)
{
    __shared__ __align__(16) _Float16 sG4[4][DTILE * H];   // 10 KB, one slice per wave

    const int t    = threadIdx.x;
    const int d0   = blockIdx.x * DTILE;
    const int lane = t & 63;
    const int wv   = t >> 6;
    const int g    = lane >> 4;
    const int n    = lane & 15;
    _Float16* sGw  = sG4[wv];

    // ---- private G build: A[m=dd][k] = [fe | fb | 1 | 0], B = w1f table, 8 MFMAs ----
    {
        const int dA = d0 + n;                      // A row m=n -> feature d0+n (rows >=DTILE unused)
        const int dAc = min(dA, D - 1);
        union AF { half8 v; _Float16 e[8]; } af;
        if (g < 2) {
            const float4* fe = (const float4*)&feat_emb[(size_t)dAc * K + g * 8];
            float4 u0 = fe[0], u1 = fe[1];
            af.e[0] = (_Float16)u0.x; af.e[1] = (_Float16)u0.y;
            af.e[2] = (_Float16)u0.z; af.e[3] = (_Float16)u0.w;
            af.e[4] = (_Float16)u1.x; af.e[5] = (_Float16)u1.y;
            af.e[6] = (_Float16)u1.z; af.e[7] = (_Float16)u1.w;
        } else if (g == 2) {
            af.e[0] = (_Float16)feat_bias[dAc];
            af.e[1] = (_Float16)1.f;
            #pragma unroll
            for (int j = 2; j < 8; ++j) af.e[j] = (_Float16)0.f;
        } else {
            #pragma unroll
            for (int j = 0; j < 8; ++j) af.e[j] = (_Float16)0.f;
        }
        #pragma unroll
        for (int c = 0; c < 8; ++c) {
            half8 bf = *(const half8*)(w1f + (((c << 6) + lane) << 3));
            f32x4 C = {0.f, 0.f, 0.f, 0.f};
            C = __builtin_amdgcn_mfma_f32_16x16x32_f16(af.v, bf, C, 0, 0, 0);
            #pragma unroll
            for (int r = 0; r < 4; ++r) {
                const int m2 = g * 4 + r;           // C row = dd
                if (m2 < DTILE) sGw[m2 * H + c * 16 + n] = (_Float16)C[r];
            }
        }
    }

    // ---- hot-loop operands (all global/L2, fully parallel) ----
    const int sample = wv * 16 + n;
    const int moff   = wv * 16 + g * 4;

    const float* xrow = x + (size_t)sample * D + d0;
    hv2 xh[DTILE / 2];
    #pragma unroll
    for (int i = 0; i < DTILE / 2; ++i) {
        float2 xv = *(const float2*)(xrow + 2 * i);
        xh[i] = (hv2){(_Float16)xv.x, (_Float16)xv.y};
    }
    hv4 mv[DTILE];                                  // mask rows, prefetched
    #pragma unroll
    for (int dd = 0; dd < DTILE; ++dd)
        mv[dd] = *(const hv4*)(mTh + (size_t)(d0 + dd) * B + moff);

    half8 Bf[4];
    #pragma unroll
    for (int s = 0; s < 4; ++s)
        Bf[s] = *(const half8*)(hiW2 + (((s * 4 + g) * 16 + n) << 3));
    hv2 w0h[4][4];
    #pragma unroll
    for (int s = 0; s < 4; ++s) {
        const float4* wp = (const float4*)&W1[s * 32 + g * 8];
        float4 a0 = wp[0], a1 = wp[1];
        w0h[s][0] = (hv2){(_Float16)a0.x, (_Float16)a0.y};
        w0h[s][1] = (hv2){(_Float16)a0.z, (_Float16)a0.w};
        w0h[s][2] = (hv2){(_Float16)a1.x, (_Float16)a1.y};
        w0h[s][3] = (hv2){(_Float16)a1.z, (_Float16)a1.w};
    }
    const float b2n = b2[n];
    const hv2 zeroh = {(_Float16)0.f, (_Float16)0.f};

    // ---- hot loop on the wave's private G slice (no barrier anywhere) ----
    f32x4 cacc = {0.f, 0.f, 0.f, 0.f};
    const _Float16* gb0 = sGw + g * 8;

    #pragma unroll
    for (int i = 0; i < DTILE / 2; ++i) {
        const int dd0 = 2 * i, dd1 = 2 * i + 1;
        const hv2 xa = {xh[i].x, xh[i].x};
        const hv2 xb = {xh[i].y, xh[i].y};
        f32x4 c1a = {b2n, b2n, b2n, b2n};
        f32x4 c1b = {b2n, b2n, b2n, b2n};
        #pragma unroll
        for (int s = 0; s < 4; ++s) {
            union GA { half8 v; hv2 p[4]; };
            GA ga, gb, A0, A1;
            ga.v = *(const half8*)(gb0 + dd0 * H + s * 32);   // broadcast ds_read_b128
            gb.v = *(const half8*)(gb0 + dd1 * H + s * 32);
            #pragma unroll
            for (int p = 0; p < 4; ++p) {
                hv2 h0 = __builtin_elementwise_fma(xa, w0h[s][p], ga.p[p]);
                hv2 h1 = __builtin_elementwise_fma(xb, w0h[s][p], gb.p[p]);
                A0.p[p] = __builtin_elementwise_max(h0, zeroh);
                A1.p[p] = __builtin_elementwise_max(h1, zeroh);
            }
            c1a = __builtin_amdgcn_mfma_f32_16x16x32_f16(A0.v, Bf[s], c1a, 0, 0, 0);
            c1b = __builtin_amdgcn_mfma_f32_16x16x32_f16(A1.v, Bf[s], c1b, 0, 0, 0);
        }
        cacc[0] = fmaf((float)mv[dd0].x, fmaxf(c1a[0], 0.f), fmaf((float)mv[dd1].x, fmaxf(c1b[0], 0.f), cacc[0]));
        cacc[1] = fmaf((float)mv[dd0].y, fmaxf(c1a[1], 0.f), fmaf((float)mv[dd1].y, fmaxf(c1b[1], 0.f), cacc[1]));
        cacc[2] = fmaf((float)mv[dd0].z, fmaxf(c1a[2], 0.f), fmaf((float)mv[dd1].z, fmaxf(c1b[2], 0.f), cacc[2]));
        cacc[3] = fmaf((float)mv[dd0].w, fmaxf(c1a[3], 0.f), fmaf((float)mv[dd1].w, fmaxf(c1b[3], 0.f), cacc[3]));
    }

    // XCD-local replica: block i -> XCD i%8 round-robin; replica stays in local L2.
    float* crep = rep + (size_t)(blockIdx.x & (NREP - 1)) * (B * K);
    #pragma unroll
    for (int r = 0; r < 4; ++r)
        atomicAdd(&crep[(moff + r) * K + n], cacc[r]);
}

// enc: reduce NREP replicas -> c[b], then 16->256->64 MLP. one block per sample.
__global__ __launch_bounds__(256) void partial_enc_kernel(
    const float* __restrict__ rep, const float* __restrict__ We1,
    const float* __restrict__ be1, const float* __restrict__ We2,
    const float* __restrict__ be2, float* __restrict__ out)
{
    const int b = blockIdx.x;
    const int t = threadIdx.x;
    __shared__ float sc[K];
    __shared__ float st1[E];
    __shared__ float red[256];

    {
        const int k = t & 15, grp = t >> 4;
        red[t] = (grp < NREP) ? rep[grp * (B * K) + b * K + k] : 0.f;
    }
    __syncthreads();
    if (t < K) {
        float s2 = 0.f;
        #pragma unroll
        for (int q = 0; q < 16; ++q) s2 += red[q * 16 + t];
        sc[t] = s2;
    }
    __syncthreads();

    {
        float acc = be1[t];
        #pragma unroll
        for (int k = 0; k < K; ++k)
            acc = fmaf(sc[k], We1[k * E + t], acc);
        st1[t] = fmaxf(acc, 0.f);
    }
    __syncthreads();

    const int j = t & 63, seg = t >> 6;
    float acc = 0.f;
    #pragma unroll 4
    for (int e = seg * 64; e < seg * 64 + 64; ++e)
        acc = fmaf(st1[e], We2[e * 64 + j], acc);
    red[t] = acc;
    __syncthreads();

    if (t < 64) {
        float v = red[j] + red[64 + j] + red[128 + j] + red[192 + j] + be2[j];
        if (j < Z) out[b * Z + j] = v;                 // mu
        else       out[B * Z + b * Z + (j - Z)] = v;   // logvar
    }
}

extern "C" void kernel_launch(void* const* d_in, const int* in_sizes, int n_in,
                              void* d_out, int out_size, void* d_ws, size_t ws_size,
                              hipStream_t stream) {
    const float* x         = (const float*)d_in[0];
    const int*   mask      = (const int*)  d_in[1];
    const float* feat_emb  = (const float*)d_in[2];
    const float* feat_bias = (const float*)d_in[3];
    const float* W1        = (const float*)d_in[4];
    const float* b1        = (const float*)d_in[5];
    const float* W2        = (const float*)d_in[6];
    const float* b2        = (const float*)d_in[7];
    const float* We1       = (const float*)d_in[8];
    const float* be1       = (const float*)d_in[9];
    const float* We2       = (const float*)d_in[10];
    const float* be2       = (const float*)d_in[11];

    float*     rep  = (float*)d_ws;
    _Float16*  hiW2 = (_Float16*)((char*)d_ws + HI_OFF);
    _Float16*  w1f  = (_Float16*)((char*)d_ws + W1F_OFF);
    _Float16*  mTh  = (_Float16*)((char*)d_ws + MT_OFF);

    prep_kernel<<<NREP + 2 + NTILE, 256, 0, stream>>>(
        mask, W1, b1, W2, rep, hiW2, w1f, mTh);
    partial_main_kernel<<<NBLK, 256, 0, stream>>>(
        x, feat_emb, feat_bias, W1, b2, hiW2, w1f, mTh, rep);
    partial_enc_kernel<<<B, 256, 0, stream>>>(
        rep, We1, be1, We2, be2, (float*)d_out);
}

// Round 15
// 116.509 us; speedup vs baseline: 1.0526x; 1.0526x over previous
//
#include <hip/hip_runtime.h>
#include <hip/hip_bf16.h>

// Problem constants
#define B 64
#define D 25000
#define K 16
#define H 128
#define E 256
#define Z 32
#define DTILE 40
#define NBLK (D / DTILE)      // 625 blocks -> ONE residency round (2.44 blocks/CU)
#define NREP 8                // one replica per XCD (blockIdx&7 == XCD round-robin)
#define NTILE ((D + 63) / 64) // 391 transpose tiles

// ws layout: rep f32[NREP*B*K] | hiW2 f16[H*K] | w1f f16[8*64*8] | mTh f16[D*B]
#define REP_BYTES (NREP * B * K * 4)
#define HI_OFF    REP_BYTES
#define W1F_OFF   (HI_OFF + H * K * 2)
#define MT_OFF    (W1F_OFF + 8 * 64 * 8 * 2)

typedef __attribute__((ext_vector_type(8))) _Float16 half8;
typedef __attribute__((ext_vector_type(4))) _Float16 hv4;
typedef __attribute__((ext_vector_type(2))) _Float16 hv2;
typedef __attribute__((ext_vector_type(4))) float f32x4;

// prep: bid<8 zero replicas; bid==8 fp16 W2 frag table; bid==9 extended-W1 frag table;
// bid>=10: mask transpose tile -> mTh[d][b] fp16 (coalesced both sides).
__global__ __launch_bounds__(256) void prep_kernel(
    const int* __restrict__ mask, const float* __restrict__ W1,
    const float* __restrict__ b1, const float* __restrict__ W2,
    float* __restrict__ rep, _Float16* __restrict__ hiW2,
    _Float16* __restrict__ w1f, _Float16* __restrict__ mTh)
{
    const int t = threadIdx.x;
    const int bid = blockIdx.x;
    if (bid < NREP) {
        for (int i = t; i < B * K; i += 256) rep[bid * B * K + i] = 0.f;
    } else if (bid == NREP) {
        for (int i = t; i < H * K; i += 256) {
            int j = i & 7, n = (i >> 3) & 15, g = (i >> 7) & 3, s = i >> 9;
            int k = s * 32 + g * 8 + j;
            hiW2[i] = (_Float16)W2[k * K + n];
        }
    } else if (bid == NREP + 1) {
        // w1f[c][lane][j]: B[k][h=c*16+n], k=(lane>>4)*8+j; k<16->W1[1+k], 16->W1[17], 17->b1, else 0
        for (int i = t; i < 8 * 64 * 8; i += 256) {
            int j = i & 7, lane = (i >> 3) & 63, c = i >> 9;
            int g = lane >> 4, n = lane & 15;
            int k = g * 8 + j, h = c * 16 + n;
            float v;
            if (k < 16)       v = W1[(1 + k) * H + h];
            else if (k == 16) v = W1[17 * H + h];
            else if (k == 17) v = b1[h];
            else              v = 0.f;
            w1f[i] = (_Float16)v;
        }
    } else {
        __shared__ float tm[64 * 65];
        const int dt0 = (bid - NREP - 2) * 64;
        const int dn  = min(64, D - dt0);
        for (int i = t; i < 64 * 64; i += 256) {
            int bb = i >> 6, dd = i & 63;           // dd fast -> coalesced global read
            if (dd < dn) tm[dd * 65 + bb] = (float)mask[(size_t)bb * D + dt0 + dd];
        }
        __syncthreads();
        for (int i = t; i < dn * 64; i += 256) {
            int dd = i >> 6, bb = i & 63;           // bb fast -> coalesced fp16 write
            mTh[(size_t)(dt0 + dd) * 64 + bb] = (_Float16)tm[dd * 65 + bb];
        }
    }
}

// main (ONE residency round): G-tile via MFMA (waves 0-2 own 16-row groups x 8 col-MFMAs);
// h1 = relu(x*w0 + G) packed fp16; h2 = relu(h1@W2+b2) fp16 MFMA (b2 in C-init);
// c += mask*h2 fp32 -> XCD-local replica atomics.
__global__ __launch_bounds__(256) void partial_main_kernel(
    const float* __restrict__ x, const float* __restrict__ feat_emb,
    const float* __restrict__ feat_bias, const float* __restrict__ W1,
    const float* __restrict__ b2, const _Float16* __restrict__ hiW2,
    const _Float16* __restrict__ w1f, const _Float16* __restrict__ mTh,
    float* __restrict__ rep)
{
    __shared__ __align__(16) _Float16 sGh[DTILE * H];   // 10 KB
    __shared__ __align__(16) _Float16 sMh[DTILE * B];   // 5 KB [dd][b]

    const int t    = threadIdx.x;
    const int d0   = blockIdx.x * DTILE;
    const int lane = t & 63;
    const int wv   = t >> 6;
    const int g    = lane >> 4;
    const int n    = lane & 15;

    // stage mask tile: contiguous dword copy (coalesced)
    {
        const unsigned* ms = (const unsigned*)(mTh + (size_t)d0 * B);
        unsigned* md = (unsigned*)sMh;
        #pragma unroll
        for (int i = t; i < DTILE * B / 2; i += 256) md[i] = ms[i];
    }

    // ---- G tile via MFMA: waves 0..2 build row-groups rg=wv (rows rg*16+m), 8 col-MFMAs ----
    if (wv < 3) {
        const int rg = wv;
        const int dA = d0 + rg * 16 + n;            // A row m=n -> feature
        const int dAc = min(dA, D - 1);
        union AF { half8 v; _Float16 e[8]; } af;
        if (g < 2) {
            const float4* fe = (const float4*)&feat_emb[(size_t)dAc * K + g * 8];
            float4 u0 = fe[0], u1 = fe[1];
            af.e[0] = (_Float16)u0.x; af.e[1] = (_Float16)u0.y;
            af.e[2] = (_Float16)u0.z; af.e[3] = (_Float16)u0.w;
            af.e[4] = (_Float16)u1.x; af.e[5] = (_Float16)u1.y;
            af.e[6] = (_Float16)u1.z; af.e[7] = (_Float16)u1.w;
        } else if (g == 2) {
            af.e[0] = (_Float16)feat_bias[dAc];
            af.e[1] = (_Float16)1.f;
            #pragma unroll
            for (int j = 2; j < 8; ++j) af.e[j] = (_Float16)0.f;
        } else {
            #pragma unroll
            for (int j = 0; j < 8; ++j) af.e[j] = (_Float16)0.f;
        }
        #pragma unroll
        for (int c = 0; c < 8; ++c) {
            half8 bf = *(const half8*)(w1f + (((c << 6) + lane) << 3));
            f32x4 C = {0.f, 0.f, 0.f, 0.f};
            C = __builtin_amdgcn_mfma_f32_16x16x32_f16(af.v, bf, C, 0, 0, 0);
            #pragma unroll
            for (int r = 0; r < 4; ++r) {
                const int dd = rg * 16 + g * 4 + r;  // C row
                if (dd < DTILE) sGh[dd * H + c * 16 + n] = (_Float16)C[r];
            }
        }
    }

    // per-lane x row (40 contiguous floats, 16B-aligned: 160B*blockIdx) -> fp16 pairs
    const int sample = wv * 16 + n;
    const float* xrow = x + (size_t)sample * D + d0;
    hv2 xh[DTILE / 2];
    #pragma unroll
    for (int i = 0; i < DTILE / 4; ++i) {
        float4 xv = *(const float4*)(xrow + 4 * i);
        xh[2 * i]     = (hv2){(_Float16)xv.x, (_Float16)xv.y};
        xh[2 * i + 1] = (hv2){(_Float16)xv.z, (_Float16)xv.w};
    }

    // per-lane W2 fragments + w0 (W1 row 0) fp16 pairs
    half8 Bf[4];
    #pragma unroll
    for (int s = 0; s < 4; ++s)
        Bf[s] = *(const half8*)(hiW2 + (((s * 4 + g) * 16 + n) << 3));
    hv2 w0h[4][4];
    #pragma unroll
    for (int s = 0; s < 4; ++s) {
        const float4* wp = (const float4*)&W1[s * 32 + g * 8];
        float4 a0 = wp[0], a1 = wp[1];
        w0h[s][0] = (hv2){(_Float16)a0.x, (_Float16)a0.y};
        w0h[s][1] = (hv2){(_Float16)a0.z, (_Float16)a0.w};
        w0h[s][2] = (hv2){(_Float16)a1.x, (_Float16)a1.y};
        w0h[s][3] = (hv2){(_Float16)a1.z, (_Float16)a1.w};
    }
    const float b2n = b2[n];
    const hv2 zeroh = {(_Float16)0.f, (_Float16)0.f};
    __syncthreads();

    f32x4 cacc = {0.f, 0.f, 0.f, 0.f};
    const int moff = wv * 16 + g * 4;
    const _Float16* gb0 = sGh + g * 8;

    #pragma unroll
    for (int i = 0; i < DTILE / 2; ++i) {
        const int dd0 = 2 * i, dd1 = 2 * i + 1;
        const hv2 xa = {xh[i].x, xh[i].x};
        const hv2 xb = {xh[i].y, xh[i].y};
        f32x4 c1a = {b2n, b2n, b2n, b2n};
        f32x4 c1b = {b2n, b2n, b2n, b2n};
        #pragma unroll
        for (int s = 0; s < 4; ++s) {
            union GA { half8 v; hv2 p[4]; };
            GA ga, gb, A0, A1;
            ga.v = *(const half8*)(gb0 + dd0 * H + s * 32);   // broadcast ds_read_b128
            gb.v = *(const half8*)(gb0 + dd1 * H + s * 32);
            #pragma unroll
            for (int p = 0; p < 4; ++p) {
                hv2 h0 = __builtin_elementwise_fma(xa, w0h[s][p], ga.p[p]);
                hv2 h1 = __builtin_elementwise_fma(xb, w0h[s][p], gb.p[p]);
                A0.p[p] = __builtin_elementwise_max(h0, zeroh);
                A1.p[p] = __builtin_elementwise_max(h1, zeroh);
            }
            c1a = __builtin_amdgcn_mfma_f32_16x16x32_f16(A0.v, Bf[s], c1a, 0, 0, 0);
            c1b = __builtin_amdgcn_mfma_f32_16x16x32_f16(A1.v, Bf[s], c1b, 0, 0, 0);
        }
        hv4 m0 = *(const hv4*)&sMh[dd0 * B + moff];
        hv4 m1 = *(const hv4*)&sMh[dd1 * B + moff];
        cacc[0] = fmaf((float)m0.x, fmaxf(c1a[0], 0.f), fmaf((float)m1.x, fmaxf(c1b[0], 0.f), cacc[0]));
        cacc[1] = fmaf((float)m0.y, fmaxf(c1a[1], 0.f), fmaf((float)m1.y, fmaxf(c1b[1], 0.f), cacc[1]));
        cacc[2] = fmaf((float)m0.z, fmaxf(c1a[2], 0.f), fmaf((float)m1.z, fmaxf(c1b[2], 0.f), cacc[2]));
        cacc[3] = fmaf((float)m0.w, fmaxf(c1a[3], 0.f), fmaf((float)m1.w, fmaxf(c1b[3], 0.f), cacc[3]));
    }

    // XCD-local replica: block i -> XCD i%8 round-robin; replica stays in local L2.
    float* crep = rep + (size_t)(blockIdx.x & (NREP - 1)) * (B * K);
    #pragma unroll
    for (int r = 0; r < 4; ++r)
        atomicAdd(&crep[(moff + r) * K + n], cacc[r]);
}

// enc: reduce NREP replicas -> c[b], then 16->256->64 MLP. one block per sample.
__global__ __launch_bounds__(256) void partial_enc_kernel(
    const float* __restrict__ rep, const float* __restrict__ We1,
    const float* __restrict__ be1, const float* __restrict__ We2,
    const float* __restrict__ be2, float* __restrict__ out)
{
    const int b = blockIdx.x;
    const int t = threadIdx.x;
    __shared__ float sc[K];
    __shared__ float st1[E];
    __shared__ float red[256];

    {
        const int k = t & 15, grp = t >> 4;
        red[t] = (grp < NREP) ? rep[grp * (B * K) + b * K + k] : 0.f;
    }
    __syncthreads();
    if (t < K) {
        float s2 = 0.f;
        #pragma unroll
        for (int q = 0; q < 16; ++q) s2 += red[q * 16 + t];
        sc[t] = s2;
    }
    __syncthreads();

    {
        float acc = be1[t];
        #pragma unroll
        for (int k = 0; k < K; ++k)
            acc = fmaf(sc[k], We1[k * E + t], acc);
        st1[t] = fmaxf(acc, 0.f);
    }
    __syncthreads();

    const int j = t & 63, seg = t >> 6;
    float acc = 0.f;
    #pragma unroll 4
    for (int e = seg * 64; e < seg * 64 + 64; ++e)
        acc = fmaf(st1[e], We2[e * 64 + j], acc);
    red[t] = acc;
    __syncthreads();

    if (t < 64) {
        float v = red[j] + red[64 + j] + red[128 + j] + red[192 + j] + be2[j];
        if (j < Z) out[b * Z + j] = v;                 // mu
        else       out[B * Z + b * Z + (j - Z)] = v;   // logvar
    }
}

extern "C" void kernel_launch(void* const* d_in, const int* in_sizes, int n_in,
                              void* d_out, int out_size, void* d_ws, size_t ws_size,
                              hipStream_t stream) {
    const float* x         = (const float*)d_in[0];
    const int*   mask      = (const int*)  d_in[1];
    const float* feat_emb  = (const float*)d_in[2];
    const float* feat_bias = (const float*)d_in[3];
    const float* W1        = (const float*)d_in[4];
    const float* b1        = (const float*)d_in[5];
    const float* W2        = (const float*)d_in[6];
    const float* b2        = (const float*)d_in[7];
    const float* We1       = (const float*)d_in[8];
    const float* be1       = (const float*)d_in[9];
    const float* We2       = (const float*)d_in[10];
    const float* be2       = (const float*)d_in[11];

    float*     rep  = (float*)d_ws;
    _Float16*  hiW2 = (_Float16*)((char*)d_ws + HI_OFF);
    _Float16*  w1f  = (_Float16*)((char*)d_ws + W1F_OFF);
    _Float16*  mTh  = (_Float16*)((char*)d_ws + MT_OFF);

    prep_kernel<<<NREP + 2 + NTILE, 256, 0, stream>>>(
        mask, W1, b1, W2, rep, hiW2, w1f, mTh);
    partial_main_kernel<<<NBLK, 256, 0, stream>>>(
        x, feat_emb, feat_bias, W1, b2, hiW2, w1f, mTh, rep);
    partial_enc_kernel<<<B, 256, 0, stream>>>(
        rep, We1, be1, We2, be2, (float*)d_out);
}

// Round 16
// 112.789 us; speedup vs baseline: 1.0873x; 1.0330x over previous
//
#include <hip/hip_runtime.h>
#include <hip/hip_bf16.h>

// Problem constants
#define B 64
#define D 25000
#define K 16
#define H 128
#define E 256
#define Z 32
#define DTILE 10
#define NBLK (D / DTILE)     // 2500 blocks
#define NREP 8               // one replica per XCD (blockIdx&7 == XCD round-robin)
#define NTILE ((D + 63) / 64) // 391 transpose tiles

// ws layout: rep f32[NREP*B*K] | hiW2 f16[H*K] | w1f f16[8*64*8] | xTh f16[D*B] | mTh f16[D*B]
#define REP_BYTES (NREP * B * K * 4)          // 32768
#define HI_OFF    REP_BYTES
#define W1F_OFF   (HI_OFF + H * K * 2)
#define XT_OFF    (W1F_OFF + 8 * 64 * 8 * 2)
#define MT_OFF    (XT_OFF + D * B * 2)

typedef __attribute__((ext_vector_type(8))) _Float16 half8;
typedef __attribute__((ext_vector_type(4))) _Float16 hv4;
typedef __attribute__((ext_vector_type(2))) _Float16 hv2;
typedef __attribute__((ext_vector_type(4))) float f32x4;

// prep: bid<8 zero replicas; bid==8 fp16 W2 frag table; bid==9 extended-W1 frag table;
// bid>=10: 64x64 LDS transpose tile -> xTh[d][b], mTh[d][b] fp16 (coalesced both sides).
__global__ __launch_bounds__(256) void prep_kernel(
    const float* __restrict__ x, const int* __restrict__ mask,
    const float* __restrict__ W1, const float* __restrict__ b1,
    const float* __restrict__ W2, float* __restrict__ rep,
    _Float16* __restrict__ hiW2, _Float16* __restrict__ w1f,
    _Float16* __restrict__ xTh, _Float16* __restrict__ mTh)
{
    const int t = threadIdx.x;
    const int bid = blockIdx.x;
    if (bid < NREP) {
        for (int i = t; i < B * K; i += 256) rep[bid * B * K + i] = 0.f;
    } else if (bid == NREP) {
        for (int i = t; i < H * K; i += 256) {
            int j = i & 7, n = (i >> 3) & 15, g = (i >> 7) & 3, s = i >> 9;
            int k = s * 32 + g * 8 + j;
            hiW2[i] = (_Float16)W2[k * K + n];
        }
    } else if (bid == NREP + 1) {
        // w1f[c][lane][j]: B[k][h=c*16+n], k=(lane>>4)*8+j; k<16->W1[1+k], 16->W1[17], 17->b1, else 0
        for (int i = t; i < 8 * 64 * 8; i += 256) {
            int j = i & 7, lane = (i >> 3) & 63, c = i >> 9;
            int g = lane >> 4, n = lane & 15;
            int k = g * 8 + j, h = c * 16 + n;
            float v;
            if (k < 16)       v = W1[(1 + k) * H + h];
            else if (k == 16) v = W1[17 * H + h];
            else if (k == 17) v = b1[h];
            else              v = 0.f;
            w1f[i] = (_Float16)v;
        }
    } else {
        __shared__ float tx[64 * 65];
        __shared__ float tm[64 * 65];
        const int dt0 = (bid - NREP - 2) * 64;
        const int dn  = min(64, D - dt0);
        for (int i = t; i < 64 * 64; i += 256) {
            int bb = i >> 6, dd = i & 63;           // dd fast -> coalesced global read
            if (dd < dn) {
                tx[dd * 65 + bb] = x[(size_t)bb * D + dt0 + dd];
                tm[dd * 65 + bb] = (float)mask[(size_t)bb * D + dt0 + dd];
            }
        }
        __syncthreads();
        for (int i = t; i < dn * 64; i += 256) {
            int dd = i >> 6, bb = i & 63;           // bb fast -> coalesced fp16 write
            xTh[(size_t)(dt0 + dd) * 64 + bb] = (_Float16)tx[dd * 65 + bb];
            mTh[(size_t)(dt0 + dd) * 64 + bb] = (_Float16)tm[dd * 65 + bb];
        }
    }
}

// main: stage contiguous fp16 x/mask tiles; G-tile via MFMA (w1f table) -> LDS fp16;
// h1 = relu(x*w0 + G) packed fp16; h2 = relu(h1@W2+b2) fp16 MFMA (b2 in C-init);
// c += mask*h2 fp32 -> XCD-local replica atomics.
__global__ __launch_bounds__(256) void partial_main_kernel(
    const float* __restrict__ feat_emb, const float* __restrict__ feat_bias,
    const float* __restrict__ W1, const float* __restrict__ b2,
    const _Float16* __restrict__ hiW2, const _Float16* __restrict__ w1f,
    const _Float16* __restrict__ xTh, const _Float16* __restrict__ mTh,
    float* __restrict__ rep)
{
    __shared__ __align__(16) _Float16 sGh[DTILE * H];   // 2.5 KB
    __shared__ __align__(16) _Float16 sXh[DTILE * B];   // 1.25 KB [dd][b]
    __shared__ __align__(16) _Float16 sMh[DTILE * B];   // 1.25 KB [dd][b]

    const int t    = threadIdx.x;
    const int d0   = blockIdx.x * DTILE;
    const int lane = t & 63;
    const int wv   = t >> 6;
    const int g    = lane >> 4;
    const int n    = lane & 15;

    // stage x/mask tiles: CONTIGUOUS dword copies (coalesced)
    {
        const unsigned* xs = (const unsigned*)(xTh + (size_t)d0 * B);
        const unsigned* ms = (const unsigned*)(mTh + (size_t)d0 * B);
        unsigned* xd = (unsigned*)sXh;
        unsigned* md = (unsigned*)sMh;
        for (int i = t; i < DTILE * B / 2; i += 256) { xd[i] = xs[i]; md[i] = ms[i]; }
    }

    // ---- G tile via MFMA: A[m=dd][k] = [fe | fb | 1 | 0], B = w1f table ----
    {
        const int m  = n;
        const int dA = min(d0 + m, D - 1);
        union AF { half8 v; _Float16 e[8]; } af;
        if (g < 2) {
            const float4* fe = (const float4*)&feat_emb[(size_t)dA * K + g * 8];
            float4 u0 = fe[0], u1 = fe[1];
            af.e[0] = (_Float16)u0.x; af.e[1] = (_Float16)u0.y;
            af.e[2] = (_Float16)u0.z; af.e[3] = (_Float16)u0.w;
            af.e[4] = (_Float16)u1.x; af.e[5] = (_Float16)u1.y;
            af.e[6] = (_Float16)u1.z; af.e[7] = (_Float16)u1.w;
        } else if (g == 2) {
            af.e[0] = (_Float16)feat_bias[dA];
            af.e[1] = (_Float16)1.f;
            #pragma unroll
            for (int j = 2; j < 8; ++j) af.e[j] = (_Float16)0.f;
        } else {
            #pragma unroll
            for (int j = 0; j < 8; ++j) af.e[j] = (_Float16)0.f;
        }
        #pragma unroll
        for (int cc = 0; cc < 2; ++cc) {
            const int c = wv * 2 + cc;
            half8 bf = *(const half8*)(w1f + (((c << 6) + lane) << 3));
            f32x4 C = {0.f, 0.f, 0.f, 0.f};
            C = __builtin_amdgcn_mfma_f32_16x16x32_f16(af.v, bf, C, 0, 0, 0);
            #pragma unroll
            for (int r = 0; r < 4; ++r) {
                const int m2 = g * 4 + r;
                if (m2 < DTILE) sGh[m2 * H + c * 16 + n] = (_Float16)C[r];
            }
        }
    }

    // per-lane W2 fragments + w0 (W1 row 0) fp16 pairs
    half8 Bf[4];
    #pragma unroll
    for (int s = 0; s < 4; ++s)
        Bf[s] = *(const half8*)(hiW2 + (((s * 4 + g) * 16 + n) << 3));
    hv2 w0h[4][4];
    #pragma unroll
    for (int s = 0; s < 4; ++s) {
        const float4* wp = (const float4*)&W1[s * 32 + g * 8];
        float4 a0 = wp[0], a1 = wp[1];
        w0h[s][0] = (hv2){(_Float16)a0.x, (_Float16)a0.y};
        w0h[s][1] = (hv2){(_Float16)a0.z, (_Float16)a0.w};
        w0h[s][2] = (hv2){(_Float16)a1.x, (_Float16)a1.y};
        w0h[s][3] = (hv2){(_Float16)a1.z, (_Float16)a1.w};
    }
    const float b2n = b2[n];
    const hv2 zeroh = {(_Float16)0.f, (_Float16)0.f};
    __syncthreads();

    // per-lane x pairs from LDS tile [dd][b]
    const int sample = wv * 16 + n;
    hv2 xh[DTILE / 2];
    #pragma unroll
    for (int i = 0; i < DTILE / 2; ++i)
        xh[i] = (hv2){sXh[(2 * i) * B + sample], sXh[(2 * i + 1) * B + sample]};

    f32x4 cacc = {0.f, 0.f, 0.f, 0.f};
    const int moff = wv * 16 + g * 4;
    const _Float16* gb0 = sGh + g * 8;

    #pragma unroll
    for (int i = 0; i < DTILE / 2; ++i) {
        const int dd0 = 2 * i, dd1 = 2 * i + 1;
        const hv2 xa = {xh[i].x, xh[i].x};
        const hv2 xb = {xh[i].y, xh[i].y};
        f32x4 c1a = {b2n, b2n, b2n, b2n};
        f32x4 c1b = {b2n, b2n, b2n, b2n};
        #pragma unroll
        for (int s = 0; s < 4; ++s) {
            union GA { half8 v; hv2 p[4]; };
            GA ga, gb, A0, A1;
            ga.v = *(const half8*)(gb0 + dd0 * H + s * 32);   // broadcast ds_read_b128
            gb.v = *(const half8*)(gb0 + dd1 * H + s * 32);
            #pragma unroll
            for (int p = 0; p < 4; ++p) {
                hv2 h0 = __builtin_elementwise_fma(xa, w0h[s][p], ga.p[p]);
                hv2 h1 = __builtin_elementwise_fma(xb, w0h[s][p], gb.p[p]);
                A0.p[p] = __builtin_elementwise_max(h0, zeroh);
                A1.p[p] = __builtin_elementwise_max(h1, zeroh);
            }
            c1a = __builtin_amdgcn_mfma_f32_16x16x32_f16(A0.v, Bf[s], c1a, 0, 0, 0);
            c1b = __builtin_amdgcn_mfma_f32_16x16x32_f16(A1.v, Bf[s], c1b, 0, 0, 0);
        }
        // mask: 4 consecutive fp16 at [dd][moff..moff+3] -> one ds_read_b64 each
        hv4 m0 = *(const hv4*)&sMh[dd0 * B + moff];
        hv4 m1 = *(const hv4*)&sMh[dd1 * B + moff];
        cacc[0] = fmaf((float)m0.x, fmaxf(c1a[0], 0.f), fmaf((float)m1.x, fmaxf(c1b[0], 0.f), cacc[0]));
        cacc[1] = fmaf((float)m0.y, fmaxf(c1a[1], 0.f), fmaf((float)m1.y, fmaxf(c1b[1], 0.f), cacc[1]));
        cacc[2] = fmaf((float)m0.z, fmaxf(c1a[2], 0.f), fmaf((float)m1.z, fmaxf(c1b[2], 0.f), cacc[2]));
        cacc[3] = fmaf((float)m0.w, fmaxf(c1a[3], 0.f), fmaf((float)m1.w, fmaxf(c1b[3], 0.f), cacc[3]));
    }

    // XCD-local replica: block i -> XCD i%8 round-robin; replica stays in local L2.
    float* crep = rep + (size_t)(blockIdx.x & (NREP - 1)) * (B * K);
    #pragma unroll
    for (int r = 0; r < 4; ++r)
        atomicAdd(&crep[(moff + r) * K + n], cacc[r]);
}

// enc: reduce NREP replicas -> c[b], then 16->256->64 MLP. one block per sample.
__global__ __launch_bounds__(256) void partial_enc_kernel(
    const float* __restrict__ rep, const float* __restrict__ We1,
    const float* __restrict__ be1, const float* __restrict__ We2,
    const float* __restrict__ be2, float* __restrict__ out)
{
    const int b = blockIdx.x;
    const int t = threadIdx.x;
    __shared__ float sc[K];
    __shared__ float st1[E];
    __shared__ float red[256];

    {
        const int k = t & 15, grp = t >> 4;
        red[t] = (grp < NREP) ? rep[grp * (B * K) + b * K + k] : 0.f;
    }
    __syncthreads();
    if (t < K) {
        float s2 = 0.f;
        #pragma unroll
        for (int q = 0; q < 16; ++q) s2 += red[q * 16 + t];
        sc[t] = s2;
    }
    __syncthreads();

    {
        float acc = be1[t];
        #pragma unroll
        for (int k = 0; k < K; ++k)
            acc = fmaf(sc[k], We1[k * E + t], acc);
        st1[t] = fmaxf(acc, 0.f);
    }
    __syncthreads();

    const int j = t & 63, seg = t >> 6;
    float acc = 0.f;
    #pragma unroll 4
    for (int e = seg * 64; e < seg * 64 + 64; ++e)
        acc = fmaf(st1[e], We2[e * 64 + j], acc);
    red[t] = acc;
    __syncthreads();

    if (t < 64) {
        float v = red[j] + red[64 + j] + red[128 + j] + red[192 + j] + be2[j];
        if (j < Z) out[b * Z + j] = v;                 // mu
        else       out[B * Z + b * Z + (j - Z)] = v;   // logvar
    }
}

extern "C" void kernel_launch(void* const* d_in, const int* in_sizes, int n_in,
                              void* d_out, int out_size, void* d_ws, size_t ws_size,
                              hipStream_t stream) {
    const float* x         = (const float*)d_in[0];
    const int*   mask      = (const int*)  d_in[1];
    const float* feat_emb  = (const float*)d_in[2];
    const float* feat_bias = (const float*)d_in[3];
    const float* W1        = (const float*)d_in[4];
    const float* b1        = (const float*)d_in[5];
    const float* W2        = (const float*)d_in[6];
    const float* b2        = (const float*)d_in[7];
    const float* We1       = (const float*)d_in[8];
    const float* be1       = (const float*)d_in[9];
    const float* We2       = (const float*)d_in[10];
    const float* be2       = (const float*)d_in[11];

    float*     rep  = (float*)d_ws;
    _Float16*  hiW2 = (_Float16*)((char*)d_ws + HI_OFF);
    _Float16*  w1f  = (_Float16*)((char*)d_ws + W1F_OFF);
    _Float16*  xTh  = (_Float16*)((char*)d_ws + XT_OFF);
    _Float16*  mTh  = (_Float16*)((char*)d_ws + MT_OFF);

    prep_kernel<<<NREP + 2 + NTILE, 256, 0, stream>>>(
        x, mask, W1, b1, W2, rep, hiW2, w1f, xTh, mTh);
    partial_main_kernel<<<NBLK, 256, 0, stream>>>(
        feat_emb, feat_bias, W1, b2, hiW2, w1f, xTh, mTh, rep);
    partial_enc_kernel<<<B, 256, 0, stream>>>(
        rep, We1, be1, We2, be2, (float*)d_out);
}